// Round 5
// baseline (400.365 us; speedup 1.0000x reference)
//
#include <hip/hip_runtime.h>
#include <hip/hip_bf16.h>
#include <cstdint>

#define NB 16
#define NC 128
#define NL 12544
#define NHD 128
#define NK 4
#define ROWS (NB*NL)
#define CH 128          /* rows per chunk */
#define PCH2 98         /* chunks per batch */

typedef unsigned short ushort_t;
typedef __attribute__((ext_vector_type(8))) short bf16x8;
typedef __attribute__((ext_vector_type(4))) float f32x4;

__device__ __forceinline__ float bf2f(unsigned u){
  union { unsigned i; float f; } v; v.i = u << 16; return v.f;
}
// fast RNE fp32->bf16 (inputs are finite/bounded here; no NaN path needed)
__device__ __forceinline__ ushort_t f2bf(float f){
  unsigned u = __float_as_uint(f);
  return (ushort_t)((u + 0x7FFFu + ((u >> 16) & 1u)) >> 16);
}

// ------- pass1 (step-0 only): folds qk-prep; x0 chunk -> LDS bf16; scores (MFMA);
// ------- block-local softmax stats; partial pooled; writes sraw + {m,S,P} ---------
__global__ void __launch_bounds__(256,4) k_pass1(const float* __restrict__ x,
    const float* __restrict__ Wk, const float* __restrict__ q,
    float* __restrict__ sraw, float* __restrict__ pm, float* __restrict__ pS,
    float* __restrict__ pP){
  __shared__ __align__(16) ushort_t xs[CH*NC];
  __shared__ float sqk[NC*2];
  __shared__ float shs0[CH], shs1[CH];
  __shared__ float red[8];
  __shared__ float pmerge[256];
  int b = blockIdx.x / PCH2, chunk = blockIdx.x % PCH2;
  int l0 = chunk*CH;
  int t = threadIdx.x, lane = t & 63, wave = t >> 6;
  int hi = lane >> 4, n16 = lane & 15;

  // stage fp32 -> bf16, XOR-swizzled
  {
    const float* src = x + ((size_t)b*NL + l0)*NC;
    #pragma unroll
    for (int i = 0; i < 16; ++i){
      int idx = i*1024 + t*4;
      int row = idx >> 7;
      float4 v = *(const float4*)(src + idx);
      unsigned p0 = (unsigned)f2bf(v.x) | ((unsigned)f2bf(v.y) << 16);
      unsigned p1 = (unsigned)f2bf(v.z) | ((unsigned)f2bf(v.w) << 16);
      *(uint2*)((char*)xs + ((idx*2) ^ ((row & 7) << 4))) = make_uint2(p0, p1);
    }
  }
  // folded prep: qk[c][h] = (Wk.q)/8
  {
    int c = t >> 1, h = t & 1;
    float s = 0.f;
    #pragma unroll 8
    for (int d = 0; d < 64; ++d) s += Wk[c*NHD + h*64 + d] * q[h*64 + d];
    sqk[c*2 + h] = s * 0.125f;
  }
  __syncthreads();

  // qk B-fragments
  bf16x8 qfv[4];
  #pragma unroll
  for (int kk = 0; kk < 4; ++kk)
    #pragma unroll
    for (int j = 0; j < 8; ++j){
      int k = kk*32 + hi*8 + j;
      qfv[kk][j] = (n16 < 2) ? (short)f2bf(sqk[k*2 + n16]) : (short)0;
    }

  // scores: 8 row-tiles, wave handles 2
  #pragma unroll
  for (int rt2 = 0; rt2 < 2; ++rt2){
    int rt = wave*2 + rt2;
    f32x4 acc = (f32x4){0.f,0.f,0.f,0.f};
    #pragma unroll
    for (int kk = 0; kk < 4; ++kk){
      int row = rt*16 + n16;
      int k = kk*32 + hi*8;
      bf16x8 a = *(const bf16x8*)((const char*)xs + ((row*256 + k*2) ^ ((row & 7) << 4)));
      acc = __builtin_amdgcn_mfma_f32_16x16x32_bf16(a, qfv[kk], acc, 0, 0, 0);
    }
    if (n16 < 2){
      float* dst = n16 ? shs1 : shs0;
      #pragma unroll
      for (int r = 0; r < 4; ++r) dst[rt*16 + hi*4 + r] = acc[r];
    }
  }
  __syncthreads();

  // block softmax stats over 128 rows
  float s0 = -3.4e38f, s1 = -3.4e38f;
  if (t < 128){
    s0 = shs0[t]; s1 = shs1[t];
    sraw[((size_t)b*2+0)*NL + l0 + t] = s0;
    sraw[((size_t)b*2+1)*NL + l0 + t] = s1;
  }
  float m0 = s0, m1 = s1;
  #pragma unroll
  for (int mk = 32; mk; mk >>= 1){ m0 = fmaxf(m0, __shfl_xor(m0, mk)); m1 = fmaxf(m1, __shfl_xor(m1, mk)); }
  if (lane == 0 && wave < 2){ red[wave] = m0; red[2+wave] = m1; }
  __syncthreads();
  float M0 = fmaxf(red[0], red[1]), M1 = fmaxf(red[2], red[3]);
  float e0 = 0.f, e1 = 0.f;
  if (t < 128){ e0 = __expf(s0 - M0); e1 = __expf(s1 - M1); shs0[t] = e0; shs1[t] = e1; }
  float t0 = e0, t1 = e1;
  #pragma unroll
  for (int mk = 32; mk; mk >>= 1){ t0 += __shfl_xor(t0, mk); t1 += __shfl_xor(t1, mk); }
  if (lane == 0 && wave < 2){ red[4+wave] = t0; red[6+wave] = t1; }
  __syncthreads();
  if (t == 0){
    pm[(b*2+0)*PCH2 + chunk] = M0; pm[(b*2+1)*PCH2 + chunk] = M1;
    pS[(b*2+0)*PCH2 + chunk] = red[4]+red[5];
    pS[(b*2+1)*PCH2 + chunk] = red[6]+red[7];
  }

  // partial pooled: P[h][c] = sum_l e_h[l]*x[l][c]
  int h = t >> 7, half = (t >> 6) & 1, cp = t & 63;
  const float* es = h ? shs1 : shs0;
  float a0 = 0.f, a1 = 0.f;
  #pragma unroll 4
  for (int i = 0; i < 64; ++i){
    int l = half*64 + i;
    float e = es[l];
    unsigned u = *(const unsigned*)((const char*)xs + ((l*256 + 4*cp) ^ ((l & 7) << 4)));
    a0 += e * bf2f(u & 0xffffu);
    a1 += e * bf2f(u >> 16);
  }
  __syncthreads();
  if (half){ pmerge[h*128 + cp*2] = a0; pmerge[h*128 + cp*2 + 1] = a1; }
  __syncthreads();
  if (!half){
    a0 += pmerge[h*128 + cp*2];
    a1 += pmerge[h*128 + cp*2 + 1];
    float2 w; w.x = a0; w.y = a1;
    *(float2*)&pP[(((size_t)b*PCH2 + chunk)*2 + h)*NC + 2*cp] = w;
  }
}

// ------- mega-gemm: per-block prologue folds combine (LSE merge + router tail +
// ------- Wcomb->lB); grid-stride over chunks; mod applied at output; STATS
// ------- epilogue produces next step's router partials from the accumulators -----
template<typename XIN, typename XOUT, bool STATS>
__global__ void __launch_bounds__(256,2) k_gemm(const XIN* __restrict__ xin,
    const float* __restrict__ Wk, const float* __restrict__ q,
    const float* __restrict__ alpha, const float* __restrict__ Wv,
    const float* __restrict__ Wmlp, const float* __restrict__ Wb,
    float* __restrict__ sraw,
    const float* __restrict__ pmR, const float* __restrict__ pSR, const float* __restrict__ pPR,
    float* __restrict__ pmW, float* __restrict__ pSW, float* __restrict__ pPW,
    XOUT* __restrict__ xout){
  __shared__ __align__(16) ushort_t lA[CH*NC];
  __shared__ __align__(16) ushort_t lB[NC*NHD];
  __shared__ float sqk[NC*2];
  __shared__ float w98[2][PCH2];
  __shared__ float pxs[2][NC];
  __shared__ float vpool[NHD];
  __shared__ float wts[NK];
  __shared__ float mSh[4];
  __shared__ float shmod[CH];
  __shared__ float shs0[CH], shs1[CH];
  __shared__ float red[8];
  __shared__ float pacc[4][2][NC];
  int b = blockIdx.x >> 5, part = blockIdx.x & 31;
  int t = threadIdx.x, lane = t & 63, wave = t >> 6;

  float av = alpha[0];
  float sp = (av > 20.f) ? av : log1pf(__expf(av));
  float sa = (float)NL * sp * 0.5f;   // fold head-mean 0.5

  // P0: qk for stats epilogue
  if (STATS){
    int c = t >> 1, h = t & 1;
    float s = 0.f;
    #pragma unroll 8
    for (int d = 0; d < 64; ++d) s += Wk[c*NHD + h*64 + d] * q[h*64 + d];
    sqk[c*2 + h] = s * 0.125f;
  }
  // P1: LSE merge across 98 chunks
  if (wave < 2){
    int h = wave;
    const float* pmh = pmR + (b*2+h)*PCH2;
    const float* pSh = pSR + (b*2+h)*PCH2;
    float m = -3.4e38f;
    for (int j = lane; j < PCH2; j += 64) m = fmaxf(m, pmh[j]);
    #pragma unroll
    for (int mk = 32; mk; mk >>= 1) m = fmaxf(m, __shfl_xor(m, mk));
    float S = 0.f;
    for (int j = lane; j < PCH2; j += 64) S += pSh[j] * __expf(pmh[j] - m);
    #pragma unroll
    for (int mk = 32; mk; mk >>= 1) S += __shfl_xor(S, mk);
    for (int j = lane; j < PCH2; j += 64) w98[h][j] = __expf(pmh[j] - m);
    if (lane == 0){ mSh[h] = m; mSh[2+h] = 1.f/S; }
  }
  __syncthreads();
  // P2: pooled merge
  {
    int h = t >> 7, c = t & 127;
    float s = 0.f;
    #pragma unroll 2
    for (int j = 0; j < PCH2; ++j) s += pPR[(((size_t)b*PCH2 + j)*2 + h)*NC + c] * w98[h][j];
    pxs[h][c] = s * mSh[2+h];
  }
  __syncthreads();
  // P3: V-projection of pooled
  if (t < NHD){
    int h = t >> 6, d = t & 63;
    float s = 0.f;
    for (int c = 0; c < NC; ++c) s += pxs[h][c] * Wv[c*NHD + h*64 + d];
    vpool[t] = s;
  }
  __syncthreads();
  // P4: routing weights (wave0, shfl softmax over 4 lanes)
  if (t < 64){
    float lg = 0.f;
    if (lane < 4){
      for (int e = 0; e < NHD; ++e) lg += vpool[e] * Wmlp[e*NK + lane];
      lg *= (1.0f/1.5f);
    }
    float m01 = fmaxf(lg, __shfl_xor(lg, 1));
    float mall = fmaxf(m01, __shfl_xor(m01, 2));
    float e = __expf(lg - mall);
    float s01 = e + __shfl_xor(e, 1);
    float sall = s01 + __shfl_xor(s01, 2);
    if (lane < 4) wts[lane] = e / sall;
  }
  __syncthreads();
  // P5: combined W^T -> lB (bf16, swizzled [d][c]); Wb reads coalesced in d
  {
    float w0 = wts[0], w1 = wts[1], w2 = wts[2], w3 = wts[3];
    for (int idx = t; idx < NC*NC; idx += 256){
      int c = idx >> 7, d = idx & 127;
      const float* wb = Wb + (size_t)c*NC + d;
      float v = w0*wb[0] + w1*wb[NC*NC] + w2*wb[2*NC*NC] + w3*wb[3*NC*NC];
      *(ushort_t*)((char*)lB + ((d*256 + c*2) ^ ((d & 7) << 4))) = f2bf(v);
    }
  }

  int trow = lane & 15, kg = lane >> 4, r0 = wave*32;
  for (int ci = part; ci < PCH2; ci += 32){
    int l0 = ci*CH;
    const float* s0p = sraw + ((size_t)b*2 + 0)*NL + l0;
    const float* s1p = sraw + ((size_t)b*2 + 1)*NL + l0;
    __syncthreads();   // lB ready (first iter) / lA,shs reuse safe (later iters)

    // stage A (pure copy for bf16; convert only for fp32) + shmod
    if constexpr (sizeof(XIN) == 4){
      const float* src = (const float*)xin + ((size_t)b*NL + l0)*NC;
      #pragma unroll
      for (int i = 0; i < 16; ++i){
        int idx = i*1024 + t*4;
        int row = idx >> 7;
        float4 v = *(const float4*)(src + idx);
        unsigned p0 = (unsigned)f2bf(v.x) | ((unsigned)f2bf(v.y) << 16);
        unsigned p1 = (unsigned)f2bf(v.z) | ((unsigned)f2bf(v.w) << 16);
        *(uint2*)((char*)lA + ((idx*2) ^ ((row & 7) << 4))) = make_uint2(p0, p1);
      }
    } else {
      const ushort_t* src = (const ushort_t*)xin + ((size_t)b*NL + l0)*NC;
      #pragma unroll
      for (int i = 0; i < 8; ++i){
        int idx = i*2048 + t*8;
        int row = idx >> 7;
        uint4 v = *(const uint4*)(src + idx);
        *(uint4*)((char*)lA + ((idx*2) ^ ((row & 7) << 4))) = v;
      }
    }
    if (t < CH)
      shmod[t] = 1.f + sa*(__expf(s0p[t]-mSh[0])*mSh[2] + __expf(s1p[t]-mSh[1])*mSh[3]);
    __syncthreads();

    // MFMA
    f32x4 acc[2][8];
    #pragma unroll
    for (int m = 0; m < 2; ++m)
      #pragma unroll
      for (int n = 0; n < 8; ++n) acc[m][n] = (f32x4){0.f,0.f,0.f,0.f};
    #pragma unroll
    for (int kk = 0; kk < 4; ++kk){
      int k = kk*32 + kg*8;
      int ra0 = r0 + trow, ra1 = r0 + 16 + trow;
      bf16x8 a0 = *(const bf16x8*)((const char*)lA + ((ra0*256 + k*2) ^ ((ra0 & 7) << 4)));
      bf16x8 a1 = *(const bf16x8*)((const char*)lA + ((ra1*256 + k*2) ^ ((ra1 & 7) << 4)));
      #pragma unroll
      for (int nt = 0; nt < 8; ++nt){
        int col = nt*16 + trow;
        bf16x8 bf = *(const bf16x8*)((const char*)lB + ((col*256 + k*2) ^ ((col & 7) << 4)));
        acc[0][nt] = __builtin_amdgcn_mfma_f32_16x16x32_bf16(a0, bf, acc[0][nt], 0, 0, 0);
        acc[1][nt] = __builtin_amdgcn_mfma_f32_16x16x32_bf16(a1, bf, acc[1][nt], 0, 0, 0);
      }
    }

    // per-lane row mods
    float md[2][4];
    #pragma unroll
    for (int m = 0; m < 2; ++m)
      #pragma unroll
      for (int r = 0; r < 4; ++r) md[m][r] = shmod[r0 + m*16 + kg*4 + r];

    // store C = acc * mod (fp32 multiply at output)
    size_t base = ((size_t)b*NL + l0)*NC;
    #pragma unroll
    for (int m = 0; m < 2; ++m)
      #pragma unroll
      for (int nt = 0; nt < 8; ++nt)
        #pragma unroll
        for (int r = 0; r < 4; ++r){
          int row = r0 + m*16 + kg*4 + r;
          int col = nt*16 + trow;
          float v = acc[m][nt][r] * md[m][r];
          if constexpr (sizeof(XOUT) == 4) ((float*)xout)[base + (size_t)row*NC + col] = v;
          else                             ((ushort_t*)xout)[base + (size_t)row*NC + col] = f2bf(v);
        }

    if (STATS){
      // scores for next step: p_h[row] = mod[row] * sum_col acc[row][col]*qk[col][h]
      float wq0[8], wq1[8];
      #pragma unroll
      for (int nt = 0; nt < 8; ++nt){
        wq0[nt] = sqk[(nt*16 + trow)*2 + 0];
        wq1[nt] = sqk[(nt*16 + trow)*2 + 1];
      }
      #pragma unroll
      for (int m = 0; m < 2; ++m)
        #pragma unroll
        for (int r = 0; r < 4; ++r){
          float p0 = 0.f, p1 = 0.f;
          #pragma unroll
          for (int nt = 0; nt < 8; ++nt){ float v = acc[m][nt][r]; p0 += v*wq0[nt]; p1 += v*wq1[nt]; }
          #pragma unroll
          for (int mk = 1; mk < 16; mk <<= 1){ p0 += __shfl_xor(p0, mk); p1 += __shfl_xor(p1, mk); }
          int idx = m*4 + r;
          if (trow == idx){
            int row = r0 + m*16 + kg*4 + r;
            shs0[row] = p0 * md[m][r]; shs1[row] = p1 * md[m][r];
          }
        }
      __syncthreads();

      // block softmax stats
      float s0 = -3.4e38f, s1 = -3.4e38f;
      if (t < 128){
        s0 = shs0[t]; s1 = shs1[t];
        sraw[((size_t)b*2+0)*NL + l0 + t] = s0;
        sraw[((size_t)b*2+1)*NL + l0 + t] = s1;
      }
      float m0 = s0, m1 = s1;
      #pragma unroll
      for (int mk = 32; mk; mk >>= 1){ m0 = fmaxf(m0, __shfl_xor(m0, mk)); m1 = fmaxf(m1, __shfl_xor(m1, mk)); }
      if (lane == 0 && wave < 2){ red[wave] = m0; red[2+wave] = m1; }
      __syncthreads();
      float M0 = fmaxf(red[0], red[1]), M1 = fmaxf(red[2], red[3]);
      float e0 = 0.f, e1 = 0.f;
      if (t < 128){ e0 = __expf(s0 - M0); e1 = __expf(s1 - M1); shs0[t] = e0; shs1[t] = e1; }
      float t0 = e0, t1 = e1;
      #pragma unroll
      for (int mk = 32; mk; mk >>= 1){ t0 += __shfl_xor(t0, mk); t1 += __shfl_xor(t1, mk); }
      if (lane == 0 && wave < 2){ red[4+wave] = t0; red[6+wave] = t1; }
      __syncthreads();
      if (t == 0){
        pmW[(b*2+0)*PCH2 + ci] = M0; pmW[(b*2+1)*PCH2 + ci] = M1;
        pSW[(b*2+0)*PCH2 + ci] = red[4]+red[5];
        pSW[(b*2+1)*PCH2 + ci] = red[6]+red[7];
      }

      // partial pooled from accumulators (mod folded into e-weights)
      float ea0[2][4], ea1[2][4];
      #pragma unroll
      for (int m = 0; m < 2; ++m)
        #pragma unroll
        for (int r = 0; r < 4; ++r){
          int row = r0 + m*16 + kg*4 + r;
          ea0[m][r] = shs0[row] * md[m][r]; ea1[m][r] = shs1[row] * md[m][r];
        }
      #pragma unroll
      for (int nt = 0; nt < 8; ++nt){
        float p0 = 0.f, p1 = 0.f;
        #pragma unroll
        for (int m = 0; m < 2; ++m)
          #pragma unroll
          for (int r = 0; r < 4; ++r){
            p0 += ea0[m][r]*acc[m][nt][r];
            p1 += ea1[m][r]*acc[m][nt][r];
          }
        p0 += __shfl_xor(p0, 16); p0 += __shfl_xor(p0, 32);
        p1 += __shfl_xor(p1, 16); p1 += __shfl_xor(p1, 32);
        int col = nt*16 + trow;
        if (kg == 0) pacc[wave][0][col] = p0;
        if (kg == 1) pacc[wave][1][col] = p1;
      }
      __syncthreads();
      {
        int h = t >> 7, c = t & 127;
        pPW[(((size_t)b*PCH2 + ci)*2 + h)*NC + c] =
          pacc[0][h][c] + pacc[1][h][c] + pacc[2][h][c] + pacc[3][h][c];
      }
    }
  }
}

extern "C" void kernel_launch(void* const* d_in, const int* in_sizes, int n_in,
                              void* d_out, int out_size, void* d_ws, size_t ws_size,
                              hipStream_t stream){
  const float* x0   = (const float*)d_in[0];
  const float* Wk   = (const float*)d_in[1];
  const float* Wv   = (const float*)d_in[2];
  const float* q    = (const float*)d_in[3];
  const float* Wmlp = (const float*)d_in[4];
  const float* Wb   = (const float*)d_in[5];
  const float* alpha= (const float*)d_in[6];
  float* out = (float*)d_out;

  char* ws = (char*)d_ws;
  float* sraw = (float*)ws;                         // B*2*L
  float* pmA  = sraw + (size_t)NB*2*NL;             // B*2*98 each
  float* pSA  = pmA + NB*2*PCH2;
  float* pmB  = pSA + NB*2*PCH2;
  float* pSB  = pmB + NB*2*PCH2;
  float* pPA  = pSB + NB*2*PCH2;                    // B*98*2*128 each
  float* pPB  = pPA + (size_t)NB*PCH2*2*NC;
  char* endf  = (char*)(pPB + (size_t)NB*PCH2*2*NC);
  size_t xoff = ((size_t)(endf - ws) + 255) & ~(size_t)255;
  ushort_t* xb = (ushort_t*)(ws + xoff);
  bool big = ws_size >= xoff + (size_t)ROWS*NC*2;

  // step-0 router stats from x0 (writes set A)
  k_pass1<<<NB*PCH2, 256, 0, stream>>>(x0, Wk, q, sraw, pmA, pSA, pPA);

  dim3 g(NB*32);
  if (big){
    k_gemm<float,    ushort_t, true ><<<g, 256, 0, stream>>>(x0, Wk, q, alpha, Wv, Wmlp, Wb,
        sraw, pmA, pSA, pPA, pmB, pSB, pPB, xb);
    k_gemm<ushort_t, ushort_t, true ><<<g, 256, 0, stream>>>(xb, Wk, q, alpha, Wv, Wmlp, Wb,
        sraw, pmB, pSB, pPB, pmA, pSA, pPA, xb);
    k_gemm<ushort_t, float,    false><<<g, 256, 0, stream>>>(xb, Wk, q, alpha, Wv, Wmlp, Wb,
        sraw, pmA, pSA, pPA, pmB, pSB, pPB, out);
  } else {
    k_gemm<float, float, true ><<<g, 256, 0, stream>>>(x0, Wk, q, alpha, Wv, Wmlp, Wb,
        sraw, pmA, pSA, pPA, pmB, pSB, pPB, out);
    k_gemm<float, float, true ><<<g, 256, 0, stream>>>(out, Wk, q, alpha, Wv, Wmlp, Wb,
        sraw, pmB, pSB, pPB, pmA, pSA, pPA, out);
    k_gemm<float, float, false><<<g, 256, 0, stream>>>(out, Wk, q, alpha, Wv, Wmlp, Wb,
        sraw, pmA, pSA, pPA, pmB, pSB, pPB, out);
  }
}